// Round 3
// baseline (71.422 us; speedup 1.0000x reference)
//
#include <hip/hip_runtime.h>

// Pairwise-KL abs-diff loss, N=128, D=4096, f32.
// loss = (1e-4 + sum_{i,j} |c[i] - M[i,j]|) / (N*N)
//   c[i]   = sum_d ( s*log s - t*log t )                       (self terms, merged)
//   M[i,j] = sum_d ( s[i,d]*log s[j,d] - t[i,d]*log t[j,d] )   (both cross matmuls, one accumulator)
//
// cross_kernel: 4 output tiles (64x64) x 128 d-chunks (32 d) = 512 blocks, 256 thr.
//   Stages s/t (i-rows) and log s / log t (j-rows) transposed into LDS [d][row]
//   (pad 68 -> 16B aligned, breaks pow2 strides). 4x4 micro-tile per thread via
//   float4 LDS reads: A-side reads are 16-lane broadcasts (bank-dedup'd ~free),
//   B-side is a 2-way wrap (free per m136) -> inner loop is VALU-bound.
//   Writes per-chunk partial M to ws (8 MiB, deterministic). Block 0 zeroes d_out
//   (saves the memset dispatch; stream ordering makes it visible to finish_kernel).
//   KNOWN TUNABLE: grid = 2 blocks/CU (2 waves/SIMD). If first profile shows
//   VALUBusy < ~40%, switch BK 32->16 (1024 blocks, 4 waves/SIMD, ws 16 MiB).
// finish_kernel: 128 blocks x 512 thr. Recomputes c[i] inline, sums 128 chunk
//   partials coalesced, |c - M|, block reduce, atomicAdd. Block 0 adds 1e-4/N^2.

#define DIM 4096
#define NROWS 128
#define BK 32    // d per chunk
#define BT 64    // output tile dim
#define NCH 128  // chunks = DIM/BK
#define PAD 68   // 68*4 B = 272 B row pitch, 16B aligned

__global__ __launch_bounds__(256) void cross_kernel(
    const float* __restrict__ S, const float* __restrict__ T,
    float* __restrict__ Mpart, float* __restrict__ out)
{
    __shared__ float sS[BK][PAD];
    __shared__ float sT[BK][PAD];
    __shared__ float sLS[BK][PAD];
    __shared__ float sLT[BK][PAD];

    const int bx   = blockIdx.x;
    const int tile = bx & 3;      // ti*2 + tj
    const int ch   = bx >> 2;     // 0..127
    const int ti = tile >> 1, tj = tile & 1;
    const int i0 = ti * BT;
    const int j0 = tj * BT;
    const int c0 = ch * BK;
    const int tid = threadIdx.x;

    if (bx == 0 && tid == 0) *out = 0.f;   // d_out is re-poisoned before every call

    // Stage: per matrix 64 rows x 32 d = 512 float4 loads; 2 per thread.
    #pragma unroll
    for (int rep = 0; rep < 2; ++rep) {
        const int f   = tid + rep * 256;   // 0..511
        const int row = f >> 3;            // 0..63
        const int dq  = (f & 7) << 2;      // 0,4,...,28

        float4 v;
        v = *(const float4*)(S + (size_t)(i0 + row) * DIM + c0 + dq);
        sS[dq + 0][row] = v.x; sS[dq + 1][row] = v.y;
        sS[dq + 2][row] = v.z; sS[dq + 3][row] = v.w;

        v = *(const float4*)(T + (size_t)(i0 + row) * DIM + c0 + dq);
        sT[dq + 0][row] = v.x; sT[dq + 1][row] = v.y;
        sT[dq + 2][row] = v.z; sT[dq + 3][row] = v.w;

        v = *(const float4*)(S + (size_t)(j0 + row) * DIM + c0 + dq);
        sLS[dq + 0][row] = __logf(v.x); sLS[dq + 1][row] = __logf(v.y);
        sLS[dq + 2][row] = __logf(v.z); sLS[dq + 3][row] = __logf(v.w);

        v = *(const float4*)(T + (size_t)(j0 + row) * DIM + c0 + dq);
        sLT[dq + 0][row] = __logf(v.x); sLT[dq + 1][row] = __logf(v.y);
        sLT[dq + 2][row] = __logf(v.z); sLT[dq + 3][row] = __logf(v.w);
    }
    __syncthreads();

    const int il4 = (tid >> 4) << 2;   // 0,4,...,60  (i within tile; 16-lane broadcast)
    const int jl4 = (tid & 15) << 2;   // 0,4,...,60  (j within tile; contiguous)

    float acc[4][4];
    #pragma unroll
    for (int a = 0; a < 4; ++a)
        #pragma unroll
        for (int b = 0; b < 4; ++b) acc[a][b] = 0.f;

    #pragma unroll 4
    for (int d = 0; d < BK; ++d) {
        const float4 av = *(const float4*)&sS[d][il4];
        const float4 tv = *(const float4*)&sT[d][il4];
        const float4 bv = *(const float4*)&sLS[d][jl4];
        const float4 uv = *(const float4*)&sLT[d][jl4];
        const float A[4] = {av.x, av.y, av.z, av.w};
        const float Tt[4] = {tv.x, tv.y, tv.z, tv.w};
        const float B[4] = {bv.x, bv.y, bv.z, bv.w};
        const float U[4] = {uv.x, uv.y, uv.z, uv.w};
        #pragma unroll
        for (int a = 0; a < 4; ++a)
            #pragma unroll
            for (int b = 0; b < 4; ++b)
                acc[a][b] += A[a] * B[b] - Tt[a] * U[b];
    }

    float* dst = Mpart + (size_t)ch * (NROWS * NROWS);
    #pragma unroll
    for (int a = 0; a < 4; ++a) {
        const float4 v = make_float4(acc[a][0], acc[a][1], acc[a][2], acc[a][3]);
        *(float4*)(dst + (size_t)(i0 + il4 + a) * NROWS + (j0 + jl4)) = v;
    }
}

__global__ __launch_bounds__(512) void finish_kernel(
    const float* __restrict__ S, const float* __restrict__ T,
    const float* __restrict__ Mpart, float* __restrict__ out)
{
    __shared__ float red[512];
    const int i   = blockIdx.x;    // output row 0..127
    const int tid = threadIdx.x;

    // Phase 1: c[i] = sum_d s*log s - t*log t  (8 elements per thread)
    float part = 0.f;
    {
        const float4 a0 = *(const float4*)(S + (size_t)i * DIM + tid * 8);
        const float4 a1 = *(const float4*)(S + (size_t)i * DIM + tid * 8 + 4);
        const float4 b0 = *(const float4*)(T + (size_t)i * DIM + tid * 8);
        const float4 b1 = *(const float4*)(T + (size_t)i * DIM + tid * 8 + 4);
        part += a0.x * __logf(a0.x) + a0.y * __logf(a0.y)
              + a0.z * __logf(a0.z) + a0.w * __logf(a0.w);
        part += a1.x * __logf(a1.x) + a1.y * __logf(a1.y)
              + a1.z * __logf(a1.z) + a1.w * __logf(a1.w);
        part -= b0.x * __logf(b0.x) + b0.y * __logf(b0.y)
              + b0.z * __logf(b0.z) + b0.w * __logf(b0.w);
        part -= b1.x * __logf(b1.x) + b1.y * __logf(b1.y)
              + b1.z * __logf(b1.z) + b1.w * __logf(b1.w);
    }
    red[tid] = part;
    __syncthreads();
    #pragma unroll
    for (int s = 256; s > 0; s >>= 1) {
        if (tid < s) red[tid] += red[tid + s];
        __syncthreads();
    }
    const float ci = red[0];
    __syncthreads();

    // Phase 2: M[i,j] = sum over 128 chunk partials (4-way split per j)
    const int j = tid & 127;
    const int q = tid >> 7;        // 0..3, each sums 32 chunks
    float sum = 0.f;
    const float* mp = Mpart + (size_t)q * 32 * (NROWS * NROWS)
                    + (size_t)i * NROWS + j;
    #pragma unroll 8
    for (int ch = 0; ch < 32; ++ch)
        sum += mp[(size_t)ch * (NROWS * NROWS)];
    red[tid] = sum;
    __syncthreads();

    float v = 0.f;
    if (tid < 128) {
        const float tot = red[tid] + red[tid + 128] + red[tid + 256] + red[tid + 384];
        v = fabsf(ci - tot);
    }
    __syncthreads();
    red[tid] = (tid < 128) ? v : 0.f;
    __syncthreads();
    #pragma unroll
    for (int s = 64; s > 0; s >>= 1) {
        if (tid < s) red[tid] += red[tid + s];
        __syncthreads();
    }
    if (tid == 0) {
        float add = red[0] * (1.0f / 16384.0f);
        if (i == 0) add += 1e-4f / 16384.0f;
        atomicAdd(out, add);
    }
}

extern "C" void kernel_launch(void* const* d_in, const int* in_sizes, int n_in,
                              void* d_out, int out_size, void* d_ws, size_t ws_size,
                              hipStream_t stream) {
    const float* S = (const float*)d_in[0];   // new_source [128][4096] f32
    const float* T = (const float*)d_in[1];   // new_target [128][4096] f32
    float* out   = (float*)d_out;             // scalar f32
    float* Mpart = (float*)d_ws;              // 128 chunks x 128 x 128 f32 = 8 MiB

    cross_kernel<<<dim3(512), dim3(256), 0, stream>>>(S, T, Mpart, out);
    finish_kernel<<<dim3(128), dim3(512), 0, stream>>>(S, T, Mpart, out);
}

// Round 5
// 70.536 us; speedup vs baseline: 1.0126x; 1.0126x over previous
//
#include <hip/hip_runtime.h>

// Pairwise-KL abs-diff loss, N=128, D=4096, f32.
// loss = (1e-4 + sum_{i,j} |c[i] - M[i,j]|) / (N*N)
//   M[i,j] = sum_d ( s[i,d]*log s[j,d] - t[i,d]*log t[j,d] )   (both cross matmuls, one accumulator)
//   KEY IDENTITY: KL(p||p)=0  =>  self_term[i] = cross[i,i], so
//   c[i] = (selfS - selfT)[i] = M[i,i]  — the diagonal of M. No separate
//   self-term pass needed; finish_kernel reads it from the summed partials.
//
// cross_kernel: 4 output tiles (64x64) x 128 d-chunks (32 d) = 512 blocks, 256 thr.
//   Stages s/t (i-rows) and log s / log t (j-rows) transposed into LDS [d][row]
//   (pad 68 -> 16B aligned). 4x4 micro-tile per thread via float4 LDS reads:
//   A-side reads are 16-lane broadcasts (bank-dedup'd), B-side 2-way wrap (free
//   per m136) -> inner loop VALU-bound (~1024 v_fma/thread). Writes per-chunk
//   partial M to ws (8 MiB, deterministic). Block 0 zeroes d_out.
//   (Staging writes are 4-way bank-conflicted (~1.58x on 32 ds_write_b32) —
//   accepted: PAD must stay %4==0 for aligned b128 reads; cost overlaps loads.)
// finish_kernel: 128 blocks x 256 thr, one output row i each. Sums 128 chunk
//   partials coalesced, ci = tot[i] (diagonal), sum_j |ci - tot[j]|, block
//   reduce, one atomicAdd per block. Block 0 adds 1e-4/N^2.
//
// Measured context (round 3): dur_us=71.4 but top-5 dispatches are all harness
// 256MiB ws re-poison fills at ~42us each; our kernels are <5us by arithmetic.
// This round (unchanged cross, cheaper finish) discriminates: small delta =>
// dur_us is overhead-dominated and we are near the addressable floor.

#define DIM 4096
#define NROWS 128
#define BK 32    // d per chunk
#define BT 64    // output tile dim
#define NCH 128  // chunks = DIM/BK
#define PAD 68   // 68*4 B = 272 B row pitch, 16B aligned

__global__ __launch_bounds__(256) void cross_kernel(
    const float* __restrict__ S, const float* __restrict__ T,
    float* __restrict__ Mpart, float* __restrict__ out)
{
    __shared__ float sS[BK][PAD];
    __shared__ float sT[BK][PAD];
    __shared__ float sLS[BK][PAD];
    __shared__ float sLT[BK][PAD];

    const int bx   = blockIdx.x;
    const int tile = bx & 3;      // ti*2 + tj
    const int ch   = bx >> 2;     // 0..127
    const int ti = tile >> 1, tj = tile & 1;
    const int i0 = ti * BT;
    const int j0 = tj * BT;
    const int c0 = ch * BK;
    const int tid = threadIdx.x;

    if (bx == 0 && tid == 0) *out = 0.f;   // d_out is re-poisoned before every call

    // Stage: per matrix 64 rows x 32 d = 512 float4 loads; 2 per thread.
    #pragma unroll
    for (int rep = 0; rep < 2; ++rep) {
        const int f   = tid + rep * 256;   // 0..511
        const int row = f >> 3;            // 0..63
        const int dq  = (f & 7) << 2;      // 0,4,...,28

        float4 v;
        v = *(const float4*)(S + (size_t)(i0 + row) * DIM + c0 + dq);
        sS[dq + 0][row] = v.x; sS[dq + 1][row] = v.y;
        sS[dq + 2][row] = v.z; sS[dq + 3][row] = v.w;

        v = *(const float4*)(T + (size_t)(i0 + row) * DIM + c0 + dq);
        sT[dq + 0][row] = v.x; sT[dq + 1][row] = v.y;
        sT[dq + 2][row] = v.z; sT[dq + 3][row] = v.w;

        v = *(const float4*)(S + (size_t)(j0 + row) * DIM + c0 + dq);
        sLS[dq + 0][row] = __logf(v.x); sLS[dq + 1][row] = __logf(v.y);
        sLS[dq + 2][row] = __logf(v.z); sLS[dq + 3][row] = __logf(v.w);

        v = *(const float4*)(T + (size_t)(j0 + row) * DIM + c0 + dq);
        sLT[dq + 0][row] = __logf(v.x); sLT[dq + 1][row] = __logf(v.y);
        sLT[dq + 2][row] = __logf(v.z); sLT[dq + 3][row] = __logf(v.w);
    }
    __syncthreads();

    const int il4 = (tid >> 4) << 2;   // 0,4,...,60  (i within tile; 16-lane broadcast)
    const int jl4 = (tid & 15) << 2;   // 0,4,...,60  (j within tile; contiguous)

    float acc[4][4];
    #pragma unroll
    for (int a = 0; a < 4; ++a)
        #pragma unroll
        for (int b = 0; b < 4; ++b) acc[a][b] = 0.f;

    #pragma unroll 4
    for (int d = 0; d < BK; ++d) {
        const float4 av = *(const float4*)&sS[d][il4];
        const float4 tv = *(const float4*)&sT[d][il4];
        const float4 bv = *(const float4*)&sLS[d][jl4];
        const float4 uv = *(const float4*)&sLT[d][jl4];
        const float A[4] = {av.x, av.y, av.z, av.w};
        const float Tt[4] = {tv.x, tv.y, tv.z, tv.w};
        const float B[4] = {bv.x, bv.y, bv.z, bv.w};
        const float U[4] = {uv.x, uv.y, uv.z, uv.w};
        #pragma unroll
        for (int a = 0; a < 4; ++a)
            #pragma unroll
            for (int b = 0; b < 4; ++b)
                acc[a][b] += A[a] * B[b] - Tt[a] * U[b];
    }

    float* dst = Mpart + (size_t)ch * (NROWS * NROWS);
    #pragma unroll
    for (int a = 0; a < 4; ++a) {
        const float4 v = make_float4(acc[a][0], acc[a][1], acc[a][2], acc[a][3]);
        *(float4*)(dst + (size_t)(i0 + il4 + a) * NROWS + (j0 + jl4)) = v;
    }
}

__global__ __launch_bounds__(256) void finish_kernel(
    const float* __restrict__ Mpart, float* __restrict__ out)
{
    __shared__ float red[256];
    __shared__ float tot[NROWS];
    const int i   = blockIdx.x;    // output row 0..127
    const int tid = threadIdx.x;

    // Sum the 128 chunk partials of row i (2-way split per column j).
    const int j = tid & 127;
    const int h = tid >> 7;        // 0..1, 64 chunks each
    float sum = 0.f;
    const float* mp = Mpart + (size_t)h * 64 * (NROWS * NROWS)
                    + (size_t)i * NROWS + j;
    #pragma unroll 8
    for (int ch = 0; ch < 64; ++ch)
        sum += mp[(size_t)ch * (NROWS * NROWS)];
    red[tid] = sum;
    __syncthreads();
    if (tid < NROWS) tot[tid] = red[tid] + red[tid + NROWS];
    __syncthreads();

    // c[i] = M[i,i] (diagonal identity). Row contribution: sum_j |c[i]-M[i,j]|.
    const float ci = tot[i];
    red[tid] = (tid < NROWS) ? fabsf(ci - tot[tid]) : 0.f;
    __syncthreads();
    #pragma unroll
    for (int s = 128; s > 0; s >>= 1) {
        if (tid < s) red[tid] += red[tid + s];
        __syncthreads();
    }
    if (tid == 0) {
        float add = red[0] * (1.0f / 16384.0f);
        if (i == 0) add += 1e-4f / 16384.0f;
        atomicAdd(out, add);
    }
}

extern "C" void kernel_launch(void* const* d_in, const int* in_sizes, int n_in,
                              void* d_out, int out_size, void* d_ws, size_t ws_size,
                              hipStream_t stream) {
    const float* S = (const float*)d_in[0];   // new_source [128][4096] f32
    const float* T = (const float*)d_in[1];   // new_target [128][4096] f32
    float* out   = (float*)d_out;             // scalar f32
    float* Mpart = (float*)d_ws;              // 128 chunks x 128 x 128 f32 = 8 MiB

    cross_kernel<<<dim3(512), dim3(256), 0, stream>>>(S, T, Mpart, out);
    finish_kernel<<<dim3(128), dim3(256), 0, stream>>>(Mpart, out);
}